// Round 5
// baseline (211.793 us; speedup 1.0000x reference)
//
#include <hip/hip_runtime.h>
#include <hip/hip_bf16.h>

#define NB 8
#define NC 256
#define NL 2048
#define ND 128
#define NROWS (NB * NL)                   // 16384 Q rows
#define QKV_ELEMS ((size_t)NB * NL * ND)  // 2,097,152
#define W_ELEMS (ND * NC)                 // 32,768
#define XS_STRIDE 264                     // 256 + 8 shorts pad: 16B-aligned rows

typedef __attribute__((ext_vector_type(8))) short bf16x8;
typedef __attribute__((ext_vector_type(4))) float f32x4;
typedef __attribute__((ext_vector_type(16))) float f32x16;
typedef __attribute__((ext_vector_type(4))) unsigned int u32x4;

__device__ __forceinline__ unsigned short f2bf(float f) {
    union { float f; unsigned u; } v; v.f = f;
    unsigned r = v.u + 0x7fffu + ((v.u >> 16) & 1u);
    return (unsigned short)(r >> 16);
}

// pack two f32 -> one u32 of 2 bf16 (lo in [15:0]) — no builtin on gfx950, use asm
__device__ __forceinline__ unsigned cvt_pk_bf16(float lo, float hi) {
    unsigned r;
    asm("v_cvt_pk_bf16_f32 %0, %1, %2" : "=v"(r) : "v"(lo), "v"(hi));
    return r;
}

// exchange upper-32-lane half of a with lower-32-lane half of b (both updated)
__device__ __forceinline__ void pl32swap(unsigned &a, unsigned &b) {
    asm("v_permlane32_swap_b32 %0, %1" : "+v"(a), "+v"(b));
}

// async global->LDS, 16 B per lane; LDS dest = uniform base + lane*16
__device__ __forceinline__ void load_lds16(const unsigned short* g, unsigned short* l) {
    __builtin_amdgcn_global_load_lds((const __attribute__((address_space(1))) unsigned int*)g,
                                     (__attribute__((address_space(3))) unsigned int*)l, 16, 0, 0);
}

// cast Wq|Wk|Wv -> contiguous bf16 buffer [3][D][C]; also zero the pair counters
__global__ void cast_w3(const float* __restrict__ wq, const float* __restrict__ wk,
                        const float* __restrict__ wv, unsigned short* __restrict__ dst,
                        int* __restrict__ cnt) {
    int i = blockIdx.x * blockDim.x + threadIdx.x;
    if (i < 256) cnt[i] = 0;
    if (i >= 3 * W_ELEMS) return;
    int sel = i / W_ELEMS, off = i - sel * W_ELEMS;
    const float* s = (sel == 0) ? wq : (sel == 1) ? wk : wv;
    dst[i] = f2bf(s[off]);
}

// xs column swizzle: XOR bits 3-5 of col with row bits; 8-short granularity so 8-aligned
// fragment reads stay contiguous. Breaks the 16-way bank conflict of the staging writes.
__device__ __forceinline__ int xs_col(int row, int col) {
    return col ^ (((row >> 2) & 7) << 3);
}

// Q/K projection sub-kernel: out[l][d] = sum_c xs[l][c] * W[d][c] + bias[d], layout [B,L,D]
__device__ __forceinline__ void qk_project(const unsigned short* xs, const unsigned short* Wb,
                                           const float* bias, unsigned short* out,
                                           int b, int l0, int wave, int ln, int quad) {
    int m0w = wave * 16;
    f32x4 acc[8] = {};
    int rowq = m0w + ln;
    #pragma unroll
    for (int s = 0; s < 8; s++) {
        bf16x8 af = *reinterpret_cast<const bf16x8*>(xs + rowq * XS_STRIDE + xs_col(rowq, s * 32 + quad * 8));
        #pragma unroll
        for (int t = 0; t < 8; t++) {
            bf16x8 bfr = *reinterpret_cast<const bf16x8*>(Wb + (size_t)(t * 16 + ln) * NC + s * 32 + quad * 8);
            acc[t] = __builtin_amdgcn_mfma_f32_16x16x32_bf16(af, bfr, acc[t], 0, 0, 0);
        }
    }
    #pragma unroll
    for (int t = 0; t < 8; t++) {
        int col = t * 16 + ln;
        float bi = bias[col];
        #pragma unroll
        for (int r = 0; r < 4; r++)
            out[(size_t)(b * NL + l0 + m0w + quad * 4 + r) * ND + col] = f2bf(acc[t][r] + bi);
    }
}

// Fused transpose+cast+projection. Reads x [b][C][L] f32 directly.
// blockIdx.x: b*32 + l-tile (64 l's). blockIdx.y: 0 = Q (xi), 1 = K AND V (xo, staged once).
// Staging: per thread 4x4 in-register transpose -> cvt_pk_bf16 -> b64 swizzled LDS writes.
__global__ __launch_bounds__(256, 4) void proj_direct(const float* __restrict__ xi,
                                                      const float* __restrict__ xo,
                                                      const unsigned short* __restrict__ Wall,
                                                      const float* __restrict__ bq,
                                                      const float* __restrict__ bk,
                                                      const float* __restrict__ bv,
                                                      unsigned short* __restrict__ Qb,
                                                      unsigned short* __restrict__ Kb,
                                                      unsigned short* __restrict__ Vtb) {
    __shared__ unsigned short xs[64 * XS_STRIDE];  // x^T tile [64 l][256 c] bf16, 33 KB
    int b = blockIdx.x >> 5, lt = blockIdx.x & 31, l0 = lt * 64;
    int y = blockIdx.y;
    int wave = threadIdx.x >> 6, lane = threadIdx.x & 63;
    int ln = lane & 15, quad = lane >> 4;

    // ---- stage: xs[l][c] = bf16(x[c][l0+l]); 4 adjacent c-rows/thread, 4x4 transpose ----
    const float* xsrc = (y == 0 ? xi : xo) + (size_t)b * NC * NL + l0;
    int l4 = ln * 4;
    #pragma unroll
    for (int G = 0; G < 4; G++) {
        int c0 = G * 64 + wave * 16 + quad * 4;
        float4 r[4];
        #pragma unroll
        for (int cc = 0; cc < 4; cc++)
            r[cc] = *reinterpret_cast<const float4*>(xsrc + (size_t)(c0 + cc) * NL + l4);
        #pragma unroll
        for (int k = 0; k < 4; k++) {
            int row = l4 + k;
            const float* f0 = reinterpret_cast<const float*>(&r[0]);
            const float* f1 = reinterpret_cast<const float*>(&r[1]);
            const float* f2 = reinterpret_cast<const float*>(&r[2]);
            const float* f3 = reinterpret_cast<const float*>(&r[3]);
            uint2 w2 = { cvt_pk_bf16(f0[k], f1[k]), cvt_pk_bf16(f2[k], f3[k]) };
            *reinterpret_cast<uint2*>(&xs[row * XS_STRIDE + xs_col(row, c0)]) = w2;
        }
    }
    __syncthreads();

    if (y == 0) {
        qk_project(xs, Wall, bq, Qb, b, l0, wave, ln, quad);
    } else {
        // ---- K ----
        qk_project(xs, Wall + W_ELEMS, bk, Kb, b, l0, wave, ln, quad);
        // ---- V: vt[d][l] = sum_c W[d][c]*xs[l][c] + bv[d], [B,D,L] ----
        const unsigned short* Wb = Wall + 2 * (size_t)W_ELEMS;
        f32x4 acc[2][4] = {};
        #pragma unroll
        for (int s = 0; s < 8; s++) {
            bf16x8 wf0 = *reinterpret_cast<const bf16x8*>(Wb + (size_t)(wave * 32 + ln) * NC + s * 32 + quad * 8);
            bf16x8 wf1 = *reinterpret_cast<const bf16x8*>(Wb + (size_t)(wave * 32 + 16 + ln) * NC + s * 32 + quad * 8);
            #pragma unroll
            for (int t = 0; t < 4; t++) {
                int rowv = t * 16 + ln;
                bf16x8 xb = *reinterpret_cast<const bf16x8*>(xs + rowv * XS_STRIDE + xs_col(rowv, s * 32 + quad * 8));
                acc[0][t] = __builtin_amdgcn_mfma_f32_16x16x32_bf16(wf0, xb, acc[0][t], 0, 0, 0);
                acc[1][t] = __builtin_amdgcn_mfma_f32_16x16x32_bf16(wf1, xb, acc[1][t], 0, 0, 0);
            }
        }
        #pragma unroll
        for (int u = 0; u < 2; u++)
            #pragma unroll
            for (int t = 0; t < 4; t++)
                #pragma unroll
                for (int r = 0; r < 4; r++) {
                    int d = wave * 32 + u * 16 + quad * 4 + r;
                    Vtb[(size_t)(b * ND + d) * NL + l0 + t * 16 + ln] = f2bf(acc[u][t][r] + bv[d]);
                }
    }
}

// Split-KV (S=2) flash attention with IN-KERNEL merge (last-block-merges, no spin):
// block = 64 q-rows x 1024 kv, grid (256, 2) -> 2 blocks/CU, 8 waves/CU = 2/SIMD.
// Each (b,qt) pair of blocks writes f32 partials; the second to finish (per-pair atomic
// counter, zeroed by cast_w3) reads its partner's partial, adds its register copy,
// normalizes, writes the final output. No merge kernel, no dispatch-order assumption.
//   kbuf[2] [64 kv][128 d]: slot j of row r holds global chunk j^(r&15)  (global_load_lds)
//   vbuf[2] [128 d][64 kv]: slot j of row d holds global chunk j^(d&7)   (global_load_lds)
// LDS 64 KB. XCD swizzle: each XCD owns one batch -> its K/V (1 MB) L2-resident.
__global__ __launch_bounds__(256, 2) void flash_attn_s2(const unsigned short* __restrict__ Q,
                                                        const unsigned short* __restrict__ K,
                                                        const unsigned short* __restrict__ Vt,
                                                        float* __restrict__ Opart,
                                                        float* __restrict__ lbuf,
                                                        int* __restrict__ cnt,
                                                        float* __restrict__ out,
                                                        int kvlen) {
    __shared__ unsigned short kbuf[2][64 * 128];
    __shared__ unsigned short vbuf[2][128 * 64];
    __shared__ int sOld;
    int bx_orig = blockIdx.x;
    int bx = ((bx_orig & 7) << 5) | (bx_orig >> 3);  // bijective XCD swizzle (256 = 8 x 32)
    int b = bx >> 5, qt = bx & 31;
    int q0 = qt * 64;
    int sp = blockIdx.y;
    int kv0 = sp * kvlen;
    int wave = threadIdx.x >> 6, lane = threadIdx.x & 63;
    int l31 = lane & 31, h = lane >> 5;
    int qg = wave >> 1, half = wave & 1;
    const float scale = 0.08838834764831845f * 1.4426950408889634f;  // 1/sqrt(128) * log2(e)

    // Q B-frags: lane holds Q[q = q0 + qg*32 + l31][k = s*16 + h*8 + j]
    bf16x8 qf[8];
    const unsigned short* qrow = Q + (size_t)(b * NL + q0 + qg * 32 + l31) * ND + h * 8;
    #pragma unroll
    for (int s = 0; s < 8; s++) qf[s] = *reinterpret_cast<const bf16x8*>(qrow + s * 16);

    float lsum = 0.f;
    f32x16 o_acc[4] = {};

    const unsigned short* kg = K + (size_t)b * NL * ND;
    const unsigned short* vg = Vt + (size_t)b * ND * NL;

    int krt = wave * 16 + (lane >> 4);  // +i*4 : K row within tile
    int kjs = (lane & 15);
    int vdt = wave * 32 + (lane >> 3);  // +i*8 : V d-row
    int vjs = (lane & 7);

    // ---- prefetch tile 0 into buffer 0 ----
    #pragma unroll
    for (int i = 0; i < 4; i++) {
        int rt = krt + i * 4;
        load_lds16(kg + (size_t)(kv0 + rt) * ND + (kjs ^ (rt & 15)) * 8, kbuf[0] + (wave * 16 + i * 4) * 128);
    }
    #pragma unroll
    for (int i = 0; i < 4; i++) {
        int dt = vdt + i * 8;
        load_lds16(vg + (size_t)dt * NL + kv0 + (vjs ^ (dt & 7)) * 8, vbuf[0] + (wave * 32 + i * 8) * 64);
    }

    int niter = kvlen >> 6;  // 16
    for (int it = 0; it < niter; it++) {
        int cur = it & 1;
        __syncthreads();  // per-wave vmcnt drain + barrier: buffer `cur` ready, buffer `cur^1` free

        // ---- issue async prefetch of next tile into the other buffer ----
        if (it + 1 < niter) {
            int kt = kv0 + (it + 1) * 64;
            int nxt = cur ^ 1;
            #pragma unroll
            for (int i = 0; i < 4; i++) {
                int rt = krt + i * 4;
                load_lds16(kg + (size_t)(kt + rt) * ND + (kjs ^ (rt & 15)) * 8, kbuf[nxt] + (wave * 16 + i * 4) * 128);
            }
            #pragma unroll
            for (int i = 0; i < 4; i++) {
                int dt = vdt + i * 8;
                load_lds16(vg + (size_t)dt * NL + kt + (vjs ^ (dt & 7)) * 8, vbuf[nxt] + (wave * 32 + i * 8) * 64);
            }
        }
        const unsigned short* kb = kbuf[cur];
        const unsigned short* vb = vbuf[cur];

        // ---- S^T tile = K Q^T : kv rows = half*32 + C-rows, q col = qg-group l31 ----
        // two independent 4-MFMA chains (even/odd s) to halve the dependency latency
        f32x16 sacc0 = {}, sacc1 = {};
        __builtin_amdgcn_s_setprio(1);
        {
            const unsigned short* krow_p = kb + (half * 32 + l31) * 128;
            #pragma unroll
            for (int s = 0; s < 8; s += 2) {
                bf16x8 kf0 = *reinterpret_cast<const bf16x8*>(krow_p + ((((s + 0) * 2 + h) ^ (l31 & 15)) << 3));
                bf16x8 kf1 = *reinterpret_cast<const bf16x8*>(krow_p + ((((s + 1) * 2 + h) ^ (l31 & 15)) << 3));
                sacc0 = __builtin_amdgcn_mfma_f32_32x32x16_bf16(kf0, qf[s], sacc0, 0, 0, 0);
                sacc1 = __builtin_amdgcn_mfma_f32_32x32x16_bf16(kf1, qf[s + 1], sacc1, 0, 0, 0);
            }
        }
        __builtin_amdgcn_s_setprio(0);

        // ---- fixed-M softmax + in-register P->bf16 B-frags (cvt_pk + permlane32_swap) ----
        float p[16];
        #pragma unroll
        for (int g = 0; g < 16; g++) p[g] = __builtin_exp2f((sacc0[g] + sacc1[g]) * scale);
        lsum += (((p[0] + p[1]) + (p[2] + p[3])) + ((p[4] + p[5]) + (p[6] + p[7])))
              + (((p[8] + p[9]) + (p[10] + p[11])) + ((p[12] + p[13]) + (p[14] + p[15])));
        unsigned c0 = cvt_pk_bf16(p[0], p[1]),   c1 = cvt_pk_bf16(p[2], p[3]);
        unsigned c2 = cvt_pk_bf16(p[4], p[5]),   c3 = cvt_pk_bf16(p[6], p[7]);
        unsigned c4 = cvt_pk_bf16(p[8], p[9]),   c5 = cvt_pk_bf16(p[10], p[11]);
        unsigned c6 = cvt_pk_bf16(p[12], p[13]), c7 = cvt_pk_bf16(p[14], p[15]);
        pl32swap(c0, c2); pl32swap(c1, c3);   // -> kv_tile 8h+{0..7}
        pl32swap(c4, c6); pl32swap(c5, c7);   // -> kv_tile 16+8h+{0..7}
        u32x4 wlo = {c0, c1, c2, c3};
        u32x4 whi = {c4, c5, c6, c7};
        bf16x8 pb0 = __builtin_bit_cast(bf16x8, wlo);  // kv = half*32 +      h*8 + j
        bf16x8 pb1 = __builtin_bit_cast(bf16x8, whi);  // kv = half*32 + 16 + h*8 + j

        // ---- O^T += V^T P^T over this wave's kv-half: steps 2*half, 2*half+1 ----
        __builtin_amdgcn_s_setprio(1);
        #pragma unroll
        for (int dt = 0; dt < 4; dt++) {
            const unsigned short* vrow = vb + (dt * 32 + l31) * 64;
            int s0 = half * 2;
            bf16x8 vf0 = *reinterpret_cast<const bf16x8*>(vrow + ((((s0 + 0) * 2 + h) ^ (l31 & 7)) << 3));
            bf16x8 vf1 = *reinterpret_cast<const bf16x8*>(vrow + ((((s0 + 1) * 2 + h) ^ (l31 & 7)) << 3));
            o_acc[dt] = __builtin_amdgcn_mfma_f32_32x32x16_bf16(vf0, pb0, o_acc[dt], 0, 0, 0);
            o_acc[dt] = __builtin_amdgcn_mfma_f32_32x32x16_bf16(vf1, pb1, o_acc[dt], 0, 0, 0);
        }
        __builtin_amdgcn_s_setprio(0);
        // no trailing barrier: next iteration's barrier protects buffer reuse
    }
    // lanes L and L+32 share q; combine their 4h-offset kv coverage
    lsum += __shfl_xor(lsum, 32);

    // ---- cross-wave (kv-half pair) reduction via LDS ----
    __syncthreads();  // all waves done with kbuf/vbuf
    float* ored = reinterpret_cast<float*>(&kbuf[0][0]);  // [2 qg][128 d][32 q] f32 = 32 KB
    float* lred = reinterpret_cast<float*>(&vbuf[0][0]);  // [2 qg][32 q]
    if (half == 1) {
        float* o = ored + qg * (128 * 32);
        #pragma unroll
        for (int dt = 0; dt < 4; dt++)
            #pragma unroll
            for (int g = 0; g < 4; g++)
                #pragma unroll
                for (int r = 0; r < 4; r++)
                    o[(dt * 32 + g * 8 + h * 4 + r) * 32 + l31] = o_acc[dt][g * 4 + r];
        if (lane < 32) lred[qg * 32 + l31] = lsum;
    }
    __syncthreads();
    int qrow_g = b * NL + q0 + qg * 32 + l31;
    float Lt = 0.f;
    if (half == 0) {
        // fold partner-wave partial into registers; write block partial to global
        float* o = ored + qg * (128 * 32);
        #pragma unroll
        for (int dt = 0; dt < 4; dt++)
            #pragma unroll
            for (int g = 0; g < 4; g++)
                #pragma unroll
                for (int r = 0; r < 4; r++)
                    o_acc[dt][g * 4 + r] += o[(dt * 32 + g * 8 + h * 4 + r) * 32 + l31];
        Lt = lsum + lred[qg * 32 + l31];
        if (lane < 32) lbuf[(size_t)sp * NROWS + qrow_g] = Lt;
        float* op = Opart + (size_t)sp * QKV_ELEMS;
        #pragma unroll
        for (int dt = 0; dt < 4; dt++) {
            #pragma unroll
            for (int g = 0; g < 4; g++) {
                f32x4 v4 = { o_acc[dt][g * 4 + 0], o_acc[dt][g * 4 + 1],
                             o_acc[dt][g * 4 + 2], o_acc[dt][g * 4 + 3] };
                *reinterpret_cast<f32x4*>(op + (size_t)qrow_g * ND + dt * 32 + g * 8 + h * 4) = v4;
            }
        }
    }
    // ---- last-block-merges: write, fence, count; second finisher merges + writes out ----
    __threadfence();                       // release: partial visible device-wide
    __syncthreads();                       // all threads' writes precede the count
    if (threadIdx.x == 0) sOld = atomicAdd(cnt + bx_orig, 1);
    __syncthreads();
    if (sOld == 1 && half == 0) {
        __threadfence();                   // acquire: partner's partial visible
        float Lo = lbuf[(size_t)(sp ^ 1) * NROWS + qrow_g];
        float inv = 1.0f / (Lt + Lo);
        const float* op = Opart + (size_t)(sp ^ 1) * QKV_ELEMS;
        #pragma unroll
        for (int dt = 0; dt < 4; dt++) {
            #pragma unroll
            for (int g = 0; g < 4; g++) {
                f32x4 pv = *reinterpret_cast<const f32x4*>(op + (size_t)qrow_g * ND + dt * 32 + g * 8 + h * 4);
                f32x4 v4;
                #pragma unroll
                for (int r = 0; r < 4; r++)
                    v4[r] = (o_acc[dt][g * 4 + r] + pv[r]) * inv;
                *reinterpret_cast<f32x4*>(out + (size_t)qrow_g * ND + dt * 32 + g * 8 + h * 4) = v4;
            }
        }
    }
}

extern "C" void kernel_launch(void* const* d_in, const int* in_sizes, int n_in,
                              void* d_out, int out_size, void* d_ws, size_t ws_size,
                              hipStream_t stream) {
    const float* x_inner = (const float*)d_in[0];
    const float* x_outer = (const float*)d_in[1];
    const float* Wq = (const float*)d_in[2];
    const float* bq = (const float*)d_in[3];
    const float* Wk = (const float*)d_in[4];
    const float* bk = (const float*)d_in[5];
    const float* Wv = (const float*)d_in[6];
    const float* bv = (const float*)d_in[7];
    float* out = (float*)d_out;

    const int S = 2;
    // workspace: [ Opart (S) ][ lbuf (S) ][ Qb ][ Kb ][ Vtb ][ Wall ][ cnt ]
    char* w = (char*)d_ws;
    float* Opart = (float*)w;                                          // [S][B*L][D] f32
    float* lbuf = (float*)(w + (size_t)S * QKV_ELEMS * 4);             // [S][B*L]
    char* w2 = w + (size_t)S * QKV_ELEMS * 4 + (size_t)S * NROWS * 4;
    unsigned short* Qb = (unsigned short*)w2;                          // [B,L,D]
    unsigned short* Kb = Qb + QKV_ELEMS;                               // [B,L,D]
    unsigned short* Vtb = Kb + QKV_ELEMS;                              // [B,D,L]
    unsigned short* Wall = Vtb + QKV_ELEMS;                            // [3][D][C]
    int* cnt = (int*)(Wall + 3 * W_ELEMS);                             // [256]

    cast_w3<<<(3 * W_ELEMS + 255) / 256, 256, 0, stream>>>(Wq, Wk, Wv, Wall, cnt);
    dim3 pgrid(NB * (NL / 64), 2);
    proj_direct<<<pgrid, 256, 0, stream>>>(x_inner, x_outer, Wall, bq, bk, bv, Qb, Kb, Vtb);
    dim3 fgrid(NB * (NL / 64), S);
    flash_attn_s2<<<fgrid, 256, 0, stream>>>(Qb, Kb, Vtb, Opart, lbuf, cnt, out, NL / S);
}

// Round 6
// 141.564 us; speedup vs baseline: 1.4961x; 1.4961x over previous
//
#include <hip/hip_runtime.h>
#include <hip/hip_bf16.h>

#define NB 8
#define NC 256
#define NL 2048
#define ND 128
#define QKV_ELEMS ((size_t)NB * NL * ND)  // 2,097,152
#define W_ELEMS (ND * NC)                 // 32,768
#define XS_STRIDE 264                     // 256 + 8 shorts pad: 16B-aligned rows

typedef __attribute__((ext_vector_type(8))) short bf16x8;
typedef __attribute__((ext_vector_type(4))) float f32x4;
typedef __attribute__((ext_vector_type(16))) float f32x16;
typedef __attribute__((ext_vector_type(4))) unsigned int u32x4;

__device__ __forceinline__ unsigned short f2bf(float f) {
    union { float f; unsigned u; } v; v.f = f;
    unsigned r = v.u + 0x7fffu + ((v.u >> 16) & 1u);
    return (unsigned short)(r >> 16);
}

// pack two f32 -> one u32 of 2 bf16 (lo in [15:0]) — no builtin on gfx950, use asm
__device__ __forceinline__ unsigned cvt_pk_bf16(float lo, float hi) {
    unsigned r;
    asm("v_cvt_pk_bf16_f32 %0, %1, %2" : "=v"(r) : "v"(lo), "v"(hi));
    return r;
}

// exchange upper-32-lane half of a with lower-32-lane half of b (both updated)
__device__ __forceinline__ void pl32swap(unsigned &a, unsigned &b) {
    asm("v_permlane32_swap_b32 %0, %1" : "+v"(a), "+v"(b));
}

// async global->LDS, 16 B per lane; LDS dest = uniform base + lane*16
__device__ __forceinline__ void load_lds16(const unsigned short* g, unsigned short* l) {
    __builtin_amdgcn_global_load_lds((const __attribute__((address_space(1))) unsigned int*)g,
                                     (__attribute__((address_space(3))) unsigned int*)l, 16, 0, 0);
}

// cast Wq|Wk|Wv -> contiguous bf16 buffer [3][D][C]
__global__ void cast_w3(const float* __restrict__ wq, const float* __restrict__ wk,
                        const float* __restrict__ wv, unsigned short* __restrict__ dst) {
    int i = blockIdx.x * blockDim.x + threadIdx.x;
    if (i >= 3 * W_ELEMS) return;
    int sel = i / W_ELEMS, off = i - sel * W_ELEMS;
    const float* s = (sel == 0) ? wq : (sel == 1) ? wk : wv;
    dst[i] = f2bf(s[off]);
}

// xs column swizzle: XOR bits 3-5 of col with row bits; 8-short granularity so 8-aligned
// fragment reads stay contiguous. Breaks the 16-way bank conflict of the staging writes.
__device__ __forceinline__ int xs_col(int row, int col) {
    return col ^ (((row >> 2) & 7) << 3);
}

// Q/K projection sub-kernel: out[l][d] = sum_c xs[l][c] * W[d][c] + bias[d], layout [B,L,D]
__device__ __forceinline__ void qk_project(const unsigned short* xs, const unsigned short* Wb,
                                           const float* bias, unsigned short* out,
                                           int b, int l0, int wave, int ln, int quad) {
    int m0w = wave * 16;
    f32x4 acc[8] = {};
    int rowq = m0w + ln;
    #pragma unroll
    for (int s = 0; s < 8; s++) {
        bf16x8 af = *reinterpret_cast<const bf16x8*>(xs + rowq * XS_STRIDE + xs_col(rowq, s * 32 + quad * 8));
        #pragma unroll
        for (int t = 0; t < 8; t++) {
            bf16x8 bfr = *reinterpret_cast<const bf16x8*>(Wb + (size_t)(t * 16 + ln) * NC + s * 32 + quad * 8);
            acc[t] = __builtin_amdgcn_mfma_f32_16x16x32_bf16(af, bfr, acc[t], 0, 0, 0);
        }
    }
    #pragma unroll
    for (int t = 0; t < 8; t++) {
        int col = t * 16 + ln;
        float bi = bias[col];
        #pragma unroll
        for (int r = 0; r < 4; r++)
            out[(size_t)(b * NL + l0 + m0w + quad * 4 + r) * ND + col] = f2bf(acc[t][r] + bi);
    }
}

// Fused transpose+cast+projection. Reads x [b][C][L] f32 directly.
// blockIdx.x: b*32 + l-tile (64 l's). blockIdx.y: 0 = Q (xi), 1 = K AND V (xo, staged once).
// Staging: per thread 4x4 in-register transpose -> cvt_pk_bf16 -> b64 swizzled LDS writes.
__global__ __launch_bounds__(256, 4) void proj_direct(const float* __restrict__ xi,
                                                      const float* __restrict__ xo,
                                                      const unsigned short* __restrict__ Wall,
                                                      const float* __restrict__ bq,
                                                      const float* __restrict__ bk,
                                                      const float* __restrict__ bv,
                                                      unsigned short* __restrict__ Qb,
                                                      unsigned short* __restrict__ Kb,
                                                      unsigned short* __restrict__ Vtb) {
    __shared__ unsigned short xs[64 * XS_STRIDE];  // x^T tile [64 l][256 c] bf16, 33 KB
    int b = blockIdx.x >> 5, lt = blockIdx.x & 31, l0 = lt * 64;
    int y = blockIdx.y;
    int wave = threadIdx.x >> 6, lane = threadIdx.x & 63;
    int ln = lane & 15, quad = lane >> 4;

    // ---- stage: xs[l][c] = bf16(x[c][l0+l]); 4 adjacent c-rows/thread, 4x4 transpose ----
    const float* xsrc = (y == 0 ? xi : xo) + (size_t)b * NC * NL + l0;
    int l4 = ln * 4;
    #pragma unroll
    for (int G = 0; G < 4; G++) {
        int c0 = G * 64 + wave * 16 + quad * 4;
        float4 r[4];
        #pragma unroll
        for (int cc = 0; cc < 4; cc++)
            r[cc] = *reinterpret_cast<const float4*>(xsrc + (size_t)(c0 + cc) * NL + l4);
        #pragma unroll
        for (int k = 0; k < 4; k++) {
            int row = l4 + k;
            const float* f0 = reinterpret_cast<const float*>(&r[0]);
            const float* f1 = reinterpret_cast<const float*>(&r[1]);
            const float* f2 = reinterpret_cast<const float*>(&r[2]);
            const float* f3 = reinterpret_cast<const float*>(&r[3]);
            uint2 w2 = { cvt_pk_bf16(f0[k], f1[k]), cvt_pk_bf16(f2[k], f3[k]) };
            *reinterpret_cast<uint2*>(&xs[row * XS_STRIDE + xs_col(row, c0)]) = w2;
        }
    }
    __syncthreads();

    if (y == 0) {
        qk_project(xs, Wall, bq, Qb, b, l0, wave, ln, quad);
    } else {
        // ---- K ----
        qk_project(xs, Wall + W_ELEMS, bk, Kb, b, l0, wave, ln, quad);
        // ---- V: vt[d][l] = sum_c W[d][c]*xs[l][c] + bv[d], [B,D,L] ----
        const unsigned short* Wb = Wall + 2 * (size_t)W_ELEMS;
        f32x4 acc[2][4] = {};
        #pragma unroll
        for (int s = 0; s < 8; s++) {
            bf16x8 wf0 = *reinterpret_cast<const bf16x8*>(Wb + (size_t)(wave * 32 + ln) * NC + s * 32 + quad * 8);
            bf16x8 wf1 = *reinterpret_cast<const bf16x8*>(Wb + (size_t)(wave * 32 + 16 + ln) * NC + s * 32 + quad * 8);
            #pragma unroll
            for (int t = 0; t < 4; t++) {
                int rowv = t * 16 + ln;
                bf16x8 xb = *reinterpret_cast<const bf16x8*>(xs + rowv * XS_STRIDE + xs_col(rowv, s * 32 + quad * 8));
                acc[0][t] = __builtin_amdgcn_mfma_f32_16x16x32_bf16(wf0, xb, acc[0][t], 0, 0, 0);
                acc[1][t] = __builtin_amdgcn_mfma_f32_16x16x32_bf16(wf1, xb, acc[1][t], 0, 0, 0);
            }
        }
        #pragma unroll
        for (int u = 0; u < 2; u++)
            #pragma unroll
            for (int t = 0; t < 4; t++)
                #pragma unroll
                for (int r = 0; r < 4; r++) {
                    int d = wave * 32 + u * 16 + quad * 4 + r;
                    Vtb[(size_t)(b * ND + d) * NL + l0 + t * 16 + ln] = f2bf(acc[u][t][r] + bv[d]);
                }
    }
}

// Single-dispatch flash attention, IN-BLOCK kv-split (no fences, no atomics, no merge):
// 512-thread block = 64 q-rows x full 2048 kv. Waves 0-3 (sp=0) process kv 0..1023,
// waves 4-7 (sp=1) kv 1024..2047, each sp-group with its own double-buffered K/V in LDS
// (128 KB total -> 1 block/CU, 8 waves = 2/SIMD, same occupancy as the split version).
// Per sp-group the structure is byte-identical to the verified S=2 kernel. Epilogue folds
// the 4 partials per qg through LDS (reusing the K/V space) and writes normalized f32 out.
//   K region [sp][cur] [64 kv][128 d]: slot j of row r holds chunk j^(r&15)  (global_load_lds)
//   V region [sp][cur] [128 d][64 kv]: slot j of row d holds chunk j^(d&7)   (global_load_lds)
// XCD swizzle: each XCD owns one batch -> its K/V (1 MB) L2-resident.
__global__ __launch_bounds__(512, 1) void flash_attn_one(const unsigned short* __restrict__ Q,
                                                         const unsigned short* __restrict__ K,
                                                         const unsigned short* __restrict__ Vt,
                                                         float* __restrict__ out) {
    __shared__ __align__(16) unsigned short smem[65536];  // 128 KB
    unsigned short* kbufp = smem;                  // [2 sp][2 cur][64*128]
    unsigned short* vbufp = smem + 2 * 2 * 64 * 128;  // [2 sp][2 cur][128*64]
    int bx = blockIdx.x;
    bx = ((bx & 7) << 5) | (bx >> 3);      // bijective XCD swizzle (256 = 8 x 32)
    int b = bx >> 5, qt = bx & 31;
    int q0 = qt * 64;
    int wave = threadIdx.x >> 6, lane = threadIdx.x & 63;
    int l31 = lane & 31, h = lane >> 5;
    int sp = wave >> 2, wave4 = wave & 3;
    int qg = wave4 >> 1, half = wave4 & 1;
    int kv0 = sp * (NL / 2);
    const float scale = 0.08838834764831845f * 1.4426950408889634f;  // 1/sqrt(128) * log2(e)

    // Q B-frags: lane holds Q[q = q0 + qg*32 + l31][k = s*16 + h*8 + j]
    bf16x8 qf[8];
    const unsigned short* qrow = Q + (size_t)(b * NL + q0 + qg * 32 + l31) * ND + h * 8;
    #pragma unroll
    for (int s = 0; s < 8; s++) qf[s] = *reinterpret_cast<const bf16x8*>(qrow + s * 16);

    float lsum = 0.f;
    f32x16 o_acc[4] = {};

    const unsigned short* kg = K + (size_t)b * NL * ND;
    const unsigned short* vg = Vt + (size_t)b * ND * NL;

    int krt = wave4 * 16 + (lane >> 4);  // +i*4 : K row within tile
    int kjs = (lane & 15);
    int vdt = wave4 * 32 + (lane >> 3);  // +i*8 : V d-row
    int vjs = (lane & 7);

    // ---- prefetch tile 0 into buffer 0 (per sp-group) ----
    {
        unsigned short* kb0 = kbufp + (sp * 2 + 0) * (64 * 128);
        unsigned short* vb0 = vbufp + (sp * 2 + 0) * (128 * 64);
        #pragma unroll
        for (int i = 0; i < 4; i++) {
            int rt = krt + i * 4;
            load_lds16(kg + (size_t)(kv0 + rt) * ND + (kjs ^ (rt & 15)) * 8, kb0 + (wave4 * 16 + i * 4) * 128);
        }
        #pragma unroll
        for (int i = 0; i < 4; i++) {
            int dt = vdt + i * 8;
            load_lds16(vg + (size_t)dt * NL + kv0 + (vjs ^ (dt & 7)) * 8, vb0 + (wave4 * 32 + i * 8) * 64);
        }
    }

    const int niter = (NL / 2) >> 6;  // 16
    for (int it = 0; it < niter; it++) {
        int cur = it & 1;
        __syncthreads();  // vmcnt drain + barrier: buffer `cur` ready, buffer `cur^1` free

        // ---- issue async prefetch of next tile into the other buffer ----
        if (it + 1 < niter) {
            int kt = kv0 + (it + 1) * 64;
            int nxt = cur ^ 1;
            unsigned short* kbn = kbufp + (sp * 2 + nxt) * (64 * 128);
            unsigned short* vbn = vbufp + (sp * 2 + nxt) * (128 * 64);
            #pragma unroll
            for (int i = 0; i < 4; i++) {
                int rt = krt + i * 4;
                load_lds16(kg + (size_t)(kt + rt) * ND + (kjs ^ (rt & 15)) * 8, kbn + (wave4 * 16 + i * 4) * 128);
            }
            #pragma unroll
            for (int i = 0; i < 4; i++) {
                int dt = vdt + i * 8;
                load_lds16(vg + (size_t)dt * NL + kt + (vjs ^ (dt & 7)) * 8, vbn + (wave4 * 32 + i * 8) * 64);
            }
        }
        const unsigned short* kb = kbufp + (sp * 2 + cur) * (64 * 128);
        const unsigned short* vb = vbufp + (sp * 2 + cur) * (128 * 64);

        // ---- S^T tile = K Q^T : kv rows = half*32 + C-rows, q col = qg-group l31 ----
        // two independent 4-MFMA chains (even/odd s) to halve the dependency latency
        f32x16 sacc0 = {}, sacc1 = {};
        __builtin_amdgcn_s_setprio(1);
        {
            const unsigned short* krow_p = kb + (half * 32 + l31) * 128;
            #pragma unroll
            for (int s = 0; s < 8; s += 2) {
                bf16x8 kf0 = *reinterpret_cast<const bf16x8*>(krow_p + ((((s + 0) * 2 + h) ^ (l31 & 15)) << 3));
                bf16x8 kf1 = *reinterpret_cast<const bf16x8*>(krow_p + ((((s + 1) * 2 + h) ^ (l31 & 15)) << 3));
                sacc0 = __builtin_amdgcn_mfma_f32_32x32x16_bf16(kf0, qf[s], sacc0, 0, 0, 0);
                sacc1 = __builtin_amdgcn_mfma_f32_32x32x16_bf16(kf1, qf[s + 1], sacc1, 0, 0, 0);
            }
        }
        __builtin_amdgcn_s_setprio(0);

        // ---- fixed-M softmax + in-register P->bf16 B-frags (cvt_pk + permlane32_swap) ----
        float p[16];
        #pragma unroll
        for (int g = 0; g < 16; g++) p[g] = __builtin_exp2f((sacc0[g] + sacc1[g]) * scale);
        lsum += (((p[0] + p[1]) + (p[2] + p[3])) + ((p[4] + p[5]) + (p[6] + p[7])))
              + (((p[8] + p[9]) + (p[10] + p[11])) + ((p[12] + p[13]) + (p[14] + p[15])));
        unsigned c0 = cvt_pk_bf16(p[0], p[1]),   c1 = cvt_pk_bf16(p[2], p[3]);
        unsigned c2 = cvt_pk_bf16(p[4], p[5]),   c3 = cvt_pk_bf16(p[6], p[7]);
        unsigned c4 = cvt_pk_bf16(p[8], p[9]),   c5 = cvt_pk_bf16(p[10], p[11]);
        unsigned c6 = cvt_pk_bf16(p[12], p[13]), c7 = cvt_pk_bf16(p[14], p[15]);
        pl32swap(c0, c2); pl32swap(c1, c3);   // -> kv_tile 8h+{0..7}
        pl32swap(c4, c6); pl32swap(c5, c7);   // -> kv_tile 16+8h+{0..7}
        u32x4 wlo = {c0, c1, c2, c3};
        u32x4 whi = {c4, c5, c6, c7};
        bf16x8 pb0 = __builtin_bit_cast(bf16x8, wlo);  // kv = half*32 +      h*8 + j
        bf16x8 pb1 = __builtin_bit_cast(bf16x8, whi);  // kv = half*32 + 16 + h*8 + j

        // ---- O^T += V^T P^T over this wave's kv-half: steps 2*half, 2*half+1 ----
        __builtin_amdgcn_s_setprio(1);
        #pragma unroll
        for (int dt = 0; dt < 4; dt++) {
            const unsigned short* vrow = vb + (dt * 32 + l31) * 64;
            int s0 = half * 2;
            bf16x8 vf0 = *reinterpret_cast<const bf16x8*>(vrow + ((((s0 + 0) * 2 + h) ^ (l31 & 7)) << 3));
            bf16x8 vf1 = *reinterpret_cast<const bf16x8*>(vrow + ((((s0 + 1) * 2 + h) ^ (l31 & 7)) << 3));
            o_acc[dt] = __builtin_amdgcn_mfma_f32_32x32x16_bf16(vf0, pb0, o_acc[dt], 0, 0, 0);
            o_acc[dt] = __builtin_amdgcn_mfma_f32_32x32x16_bf16(vf1, pb1, o_acc[dt], 0, 0, 0);
        }
        __builtin_amdgcn_s_setprio(0);
        // no trailing barrier: next iteration's barrier protects buffer reuse
    }
    // lanes L and L+32 share q; combine their 4h-offset kv coverage
    lsum += __shfl_xor(lsum, 32);

    // ---- fold 4 partials per qg (sp x half) through LDS; write normalized f32 out ----
    __syncthreads();  // all waves done with K/V buffers
    float* ored = reinterpret_cast<float*>(smem);              // [2 qg][3 slot][128 d][32 q] = 96 KB
    float* lred = reinterpret_cast<float*>(smem) + 2 * 3 * 128 * 32;  // [2 qg][3 slot][32]
    int idx = sp * 2 + half;
    if (idx > 0) {
        float* o = ored + (qg * 3 + (idx - 1)) * (128 * 32);
        #pragma unroll
        for (int dt = 0; dt < 4; dt++)
            #pragma unroll
            for (int g = 0; g < 4; g++)
                #pragma unroll
                for (int r = 0; r < 4; r++)
                    o[(dt * 32 + g * 8 + h * 4 + r) * 32 + l31] = o_acc[dt][g * 4 + r];
        if (lane < 32) lred[(qg * 3 + (idx - 1)) * 32 + l31] = lsum;
    }
    __syncthreads();
    if (idx == 0) {
        float Lt = lsum + lred[(qg * 3 + 0) * 32 + l31]
                        + lred[(qg * 3 + 1) * 32 + l31]
                        + lred[(qg * 3 + 2) * 32 + l31];
        float inv = 1.0f / Lt;
        int qrow_g = b * NL + q0 + qg * 32 + l31;
        const float* o0 = ored + (qg * 3 + 0) * (128 * 32);
        const float* o1 = ored + (qg * 3 + 1) * (128 * 32);
        const float* o2 = ored + (qg * 3 + 2) * (128 * 32);
        #pragma unroll
        for (int dt = 0; dt < 4; dt++) {
            #pragma unroll
            for (int g = 0; g < 4; g++) {
                f32x4 v4;
                #pragma unroll
                for (int r = 0; r < 4; r++) {
                    int di = (dt * 32 + g * 8 + h * 4 + r) * 32 + l31;
                    v4[r] = (o_acc[dt][g * 4 + r] + o0[di] + o1[di] + o2[di]) * inv;
                }
                *reinterpret_cast<f32x4*>(out + (size_t)qrow_g * ND + dt * 32 + g * 8 + h * 4) = v4;
            }
        }
    }
}

extern "C" void kernel_launch(void* const* d_in, const int* in_sizes, int n_in,
                              void* d_out, int out_size, void* d_ws, size_t ws_size,
                              hipStream_t stream) {
    const float* x_inner = (const float*)d_in[0];
    const float* x_outer = (const float*)d_in[1];
    const float* Wq = (const float*)d_in[2];
    const float* bq = (const float*)d_in[3];
    const float* Wk = (const float*)d_in[4];
    const float* bk = (const float*)d_in[5];
    const float* Wv = (const float*)d_in[6];
    const float* bv = (const float*)d_in[7];
    float* out = (float*)d_out;

    // workspace: [ Qb ][ Kb ][ Vtb ][ Wall ]
    char* w = (char*)d_ws;
    unsigned short* Qb = (unsigned short*)w;                 // [B,L,D]
    unsigned short* Kb = Qb + QKV_ELEMS;                     // [B,L,D]
    unsigned short* Vtb = Kb + QKV_ELEMS;                    // [B,D,L]
    unsigned short* Wall = Vtb + QKV_ELEMS;                  // [3][D][C]

    cast_w3<<<(3 * W_ELEMS + 255) / 256, 256, 0, stream>>>(Wq, Wk, Wv, Wall);
    dim3 pgrid(NB * (NL / 64), 2);
    proj_direct<<<pgrid, 256, 0, stream>>>(x_inner, x_outer, Wall, bq, bk, bv, Qb, Kb, Vtb);
    flash_attn_one<<<NB * (NL / 64), 512, 0, stream>>>(Qb, Kb, Vtb, out);
}